// Round 8
// baseline (293.944 us; speedup 1.0000x reference)
//
#include <hip/hip_runtime.h>

// GuidedAttention: B=64, Lq=Lk=512, E=64, H=8, D=8
// out  = [B,512,64] fp32, attn_wts = [B,512,512] fp32 (concatenated in d_out)
//
// v9 = v8 + MFMA epilogue.
// v8 (R7, 109us attn, VALU 72%): fragment-major K/V from ga_proj (one MFMA
// A-frag = one coalesced 256B wave load, L2-hot), two-pass softmax (pass A:
// head-per-wave denominators, shfl-only; pass B: key-split with inv pre-known,
// attn_wts in regs, PV online, ctx via LDS atomics). Zero bank conflicts,
// zero spill, 3 barriers.
// v9 changes (attn was VALU-bound; scalar epilogue = ~45% of VALU instrs
// while MFMA sat 90% idle):
//  - epilogue matmuls (Wo/W1/W2) now MFMA: 4 mfma/wave each, A-frag from LDS
//    (ctx f32->f16 / x,h f16 direct), B-frag = W read DIRECTLY from global
//    (12 gather loads/wave total, L1-hot across all 2048 blocks).
//  - LN row stats: per-quad shfl_xor over l16 + 512B cross-wave partials.
//  - wbf (26KB) deleted -> LDS 37.6K -> 12.3K -> occupancy limit moves from
//    4 blocks/CU (LDS) to 8 blocks/CU (wave cap), VGPR ~56-70 (cap 84 via
//    launch_bounds(256,6); R2/R5 spill mode excluded: live << cap).

using half4   = __attribute__((ext_vector_type(4))) _Float16;
using floatx4 = __attribute__((ext_vector_type(4))) float;

// ---------------------------------------------------------------- projection
// out[row][e] = sum_k x[row][k] * W[e][k]  (+bias; type0 also *scale*log2e)
// MFMA 16x16x16: A[m=row][k] from x, B[k][n=e] from W (B-frag lane reads
// W[n0+l16][kt*16+quad*4..]), C[m=quad*4+r][n=l16].
__global__ __launch_bounds__(256) void ga_proj(
    const float* __restrict__ q, const float* __restrict__ k,
    const float* __restrict__ Wq, const float* __restrict__ bq,
    const float* __restrict__ Wk, const float* __restrict__ bk,
    const float* __restrict__ Wv, const float* __restrict__ bv,
    _Float16* __restrict__ qws, _Float16* __restrict__ kfrag,
    _Float16* __restrict__ vfrag)
{
    const int type = blockIdx.y;                 // 0=q, 1=k, 2=v
    const int row0 = blockIdx.x * 64;            // 64 token-rows per block
    const float* __restrict__ src  = (type == 0) ? q : k;
    const float* __restrict__ W    = (type == 0) ? Wq : (type == 1) ? Wk : Wv;
    const float* __restrict__ bias = (type == 0) ? bq : (type == 1) ? bk : bv;

    __shared__ _Float16 xb16[64 * 72];   // x rows f16, stride 72
    __shared__ _Float16 wb16[64 * 72];   // W [e][k] f16

    const int t = threadIdx.x;
    #pragma unroll
    for (int j = 0; j < 4; ++j) {                // stage x and W, f32 -> f16
        int f = t + 256 * j;                     // 1024 float4 = 64x64
        int row = f >> 4, k0 = (f & 15) << 2;
        float4 v4 = *(const float4*)(src + (size_t)(row0 + row) * 64 + k0);
        half4 h4;
        h4[0] = (_Float16)v4.x; h4[1] = (_Float16)v4.y;
        h4[2] = (_Float16)v4.z; h4[3] = (_Float16)v4.w;
        *(half4*)&xb16[row * 72 + k0] = h4;
        float4 w4 = *(const float4*)(W + row * 64 + k0);
        half4 g4;
        g4[0] = (_Float16)w4.x; g4[1] = (_Float16)w4.y;
        g4[2] = (_Float16)w4.z; g4[3] = (_Float16)w4.w;
        *(half4*)&wb16[row * 72 + k0] = g4;
    }
    __syncthreads();

    const int lane = t & 63;
    const int w = t >> 6;            // wave owns 16 rows
    const int quad = lane >> 4;
    const int l16 = lane & 15;
    const int m0 = w * 16;
    const int grow = row0 + m0;      // global row base (multiple of 16)
    const int bb = grow >> 9;        // batch
    const int cc = (grow & 511) >> 4;// key-chunk (constant per wave)
    const floatx4 zf4 = {0.f, 0.f, 0.f, 0.f};

    #pragma unroll
    for (int n = 0; n < 4; ++n) {    // output-col tiles of 16
        floatx4 acc = zf4;
        #pragma unroll
        for (int kt = 0; kt < 4; ++kt) {
            half4 a4 = *(const half4*)&xb16[(m0 + l16) * 72 + kt * 16 + quad * 4];
            half4 b4 = *(const half4*)&wb16[(n * 16 + l16) * 72 + kt * 16 + quad * 4];
            acc = __builtin_amdgcn_mfma_f32_16x16x16f16(a4, b4, acc, 0, 0, 0);
        }
        const int e = n * 16 + l16;
        const float bv = bias[e];
        #pragma unroll
        for (int r = 0; r < 4; ++r) {
            float a = acc[r] + bv;
            if (type == 0) a *= 0.51012811866f;  // 1/sqrt(8) * log2(e)
            _Float16 hv = (_Float16)a;
            const int kk = quad * 4 + r;         // row-in-chunk / key16
            if (type == 0)
                qws[(size_t)(grow + kk) * 64 + e] = hv;
            else if (type == 1)   // kfrag[b][h][c][key16][8e]
                kfrag[((size_t)(bb * 8 + (e >> 3)) * 32 + cc) * 128
                      + kk * 8 + (e & 7)] = hv;
            else                  // vfrag[b][h][c][d8][key16]
                vfrag[((size_t)(bb * 8 + (e >> 3)) * 32 + cc) * 128
                      + (e & 7) * 16 + kk] = hv;
        }
    }
}

// ---------------------------------------------------------------- attention + epilogue
__global__ __launch_bounds__(256, 6) void ga_attn(
    const _Float16* __restrict__ qws, const _Float16* __restrict__ kfrag,
    const _Float16* __restrict__ vfrag,
    const float* __restrict__ prev,
    const float* __restrict__ Wo, const float* __restrict__ bo,
    const float* __restrict__ ln1g, const float* __restrict__ ln1b,
    const float* __restrict__ W1, const float* __restrict__ b1,
    const float* __restrict__ W2, const float* __restrict__ b2,
    const float* __restrict__ ln2g, const float* __restrict__ ln2b,
    float* __restrict__ out, float* __restrict__ attn)
{
    // 12,288 B LDS -> occupancy limited only by waves/VGPR (target 8 blocks/CU)
    __shared__ __align__(16) unsigned char smem[12288];
    _Float16* qb   = (_Float16*)smem;              // [16][72] f16     2304 B
    float*    inv8 = (float*)(smem + 2304);        // [8][16]  f32      512 B
    float*    ctxb = (float*)(smem + 2816);        // [16][68] f32     4352 B
    _Float16* xbf  = (_Float16*)(smem + 7168);     // [16][72] f16     2304 B
    _Float16* hbf  = (_Float16*)(smem + 9472);     // [16][72] f16     2304 B
    float*    lnp1 = (float*)(smem + 11776);       // [16][4]  f32      256 B
    float*    lnp2 = (float*)(smem + 12032);       // [16][4]  f32      256 B

    const int t = threadIdx.x;
    const int lane = t & 63;
    const int w = t >> 6;            // wave 0..3
    const int quad = lane >> 4;
    const int l16 = lane & 15;
    // XCD swizzle: b = bx&63 -> all 32 tiles of batch b on XCD b%8 (L2 locality)
    const int b  = blockIdx.x & 63;
    const int l0 = (blockIdx.x >> 6) << 4;

    const _Float16* kfb = kfrag + (size_t)b * 32768;   // 8h x 32c x 128
    const _Float16* vfb = vfrag + (size_t)b * 32768;

    // ---- stage Q tile (16 rows), zero ctx
    if (t < 128) {
        int row = t >> 3, off = (t & 7) << 3;
        *(float4*)&qb[row * 72 + off] =
            *(const float4*)(qws + ((size_t)b * 512 + l0 + row) * 64 + off);
    }
    for (int i = t; i < 16 * 68; i += 256) ctxb[i] = 0.f;
    __syncthreads();

    const floatx4 zf4 = {0.f, 0.f, 0.f, 0.f};
    const _Float16 hz = (_Float16)0.f;

    // ---- pass A: denominators. wave w owns heads {w, w+4}, all 512 keys.
    #pragma unroll 1
    for (int hi = 0; hi < 2; ++hi) {
        const int h = hi * 4 + w;
        half4 bfrag = {hz, hz, hz, hz};
        if (quad < 2) bfrag = *(const half4*)&qb[l16 * 72 + h * 8 + quad * 4];
        const _Float16* kb = kfb + (size_t)h * 4096 + l16 * 8 + (quad & 1) * 4;
        float psum = 0.f;
        #pragma unroll 8
        for (int c = 0; c < 32; ++c) {
            // A[m=key16=l16][k]: k>=8 duplicates k<8 (finite; bfrag=0 there)
            half4 af = *(const half4*)(kb + c * 128);
            floatx4 sv = __builtin_amdgcn_mfma_f32_16x16x16f16(af, bfrag, zf4, 0, 0, 0);
            psum += (exp2f(sv[0]) + exp2f(sv[1])) + (exp2f(sv[2]) + exp2f(sv[3]));
        }
        psum += __shfl_xor(psum, 16);   // quads hold disjoint key subsets
        psum += __shfl_xor(psum, 32);
        if (lane < 16) inv8[h * 16 + l16] = 1.0f / psum;
    }
    __syncthreads();

    // ---- pass B: key-split (wave w owns keys [w*128,+128)), inv pre-known.
    // No per-head barrier. attn accumulates in regs (wave-exclusive columns).
    floatx4 attn_acc[8];
    #pragma unroll
    for (int i = 0; i < 8; ++i) attn_acc[i] = zf4;

    #pragma unroll 1
    for (int h = 0; h < 8; ++h) {
        half4 bfrag = {hz, hz, hz, hz};
        if (quad < 2) bfrag = *(const half4*)&qb[l16 * 72 + h * 8 + quad * 4];
        const float inv = inv8[h * 16 + l16];
        const _Float16* kb = kfb + ((size_t)h * 32 + w * 8) * 128 + l16 * 8 + (quad & 1) * 4;
        const _Float16* vb = vfb + ((size_t)h * 32 + w * 8) * 128 + (l16 & 7) * 16 + quad * 4;
        floatx4 cacc0 = zf4, cacc1 = zf4;
        #pragma unroll
        for (int c = 0; c < 8; ++c) {
            half4 af = *(const half4*)(kb + c * 128);
            floatx4 sv = __builtin_amdgcn_mfma_f32_16x16x16f16(af, bfrag, zf4, 0, 0, 0);
            float e0 = exp2f(sv[0]), e1 = exp2f(sv[1]);
            float e2 = exp2f(sv[2]), e3 = exp2f(sv[3]);
            floatx4 ev; ev[0] = e0 * inv; ev[1] = e1 * inv;
            ev[2] = e2 * inv; ev[3] = e3 * inv;
            attn_acc[c] += ev;
            half4 ph;
            ph[0] = (_Float16)e0; ph[1] = (_Float16)e1;
            ph[2] = (_Float16)e2; ph[3] = (_Float16)e3;
            // A-frag = V^T: A[d=l16&7][k=key=quad*4+j]; P^T C-layout == B-layout
            half4 vf = *(const half4*)(vb + c * 128);
            if (c & 1) cacc1 = __builtin_amdgcn_mfma_f32_16x16x16f16(vf, ph, cacc1, 0, 0, 0);
            else       cacc0 = __builtin_amdgcn_mfma_f32_16x16x16f16(vf, ph, cacc0, 0, 0, 0);
        }
        floatx4 cs = (cacc0 + cacc1) * inv;
        if (quad < 2) {                  // ctx^T[d=quad*4+r][q=l16], d<8 real
            #pragma unroll
            for (int r = 0; r < 4; ++r)
                atomicAdd(&ctxb[l16 * 68 + h * 8 + quad * 4 + r], cs[r]);
        }
    }
    // attn_wts store: rows=l16, this wave's 128 key-cols (mean over heads)
    {
        float* ap = attn + ((size_t)b * 512 + l0 + l16) * 512 + w * 128 + quad * 4;
        #pragma unroll
        for (int c = 0; c < 8; ++c)
            *(floatx4*)(ap + c * 16) = attn_acc[c] * 0.125f;
    }
    __syncthreads();   // ctx atomics complete

    // ---- MFMA epilogue. out[l][e] = ...: A[m=l][k], B[k][n=e]=W[e][k];
    // lane's C covers rows l=quad*4+r, col e=w*16+l16 (same mapping as proj).
    const int ecol = w * 16 + l16;
    const size_t orow = (size_t)b * 512 + l0;
    float y[4], xn[4];

    {   // stage 1: ctx@Wo.T + bo + prev -> LN1 -> xbf (+xn regs for residual)
        floatx4 acc = zf4;
        #pragma unroll
        for (int kt = 0; kt < 4; ++kt) {
            floatx4 cx = *(const floatx4*)&ctxb[l16 * 68 + kt * 16 + quad * 4];
            half4 a4;
            a4[0] = (_Float16)cx[0]; a4[1] = (_Float16)cx[1];
            a4[2] = (_Float16)cx[2]; a4[3] = (_Float16)cx[3];
            float4 wv = *(const float4*)(Wo + (size_t)ecol * 64 + kt * 16 + quad * 4);
            half4 b4;
            b4[0] = (_Float16)wv.x; b4[1] = (_Float16)wv.y;
            b4[2] = (_Float16)wv.z; b4[3] = (_Float16)wv.w;
            acc = __builtin_amdgcn_mfma_f32_16x16x16f16(a4, b4, acc, 0, 0, 0);
        }
        const float bov = bo[ecol], g1v = ln1g[ecol], b1v = ln1b[ecol];
        float s1[4], s2[4];
        #pragma unroll
        for (int r = 0; r < 4; ++r) {
            y[r] = acc[r] + bov + prev[(orow + quad * 4 + r) * 64 + ecol];
            s1[r] = y[r]; s2[r] = y[r] * y[r];
        }
        #pragma unroll
        for (int o = 1; o < 16; o <<= 1) {
            #pragma unroll
            for (int r = 0; r < 4; ++r) {
                s1[r] += __shfl_xor(s1[r], o);
                s2[r] += __shfl_xor(s2[r], o);
            }
        }
        if (l16 == 0) {
            #pragma unroll
            for (int r = 0; r < 4; ++r) {
                lnp1[(quad * 4 + r) * 4 + w] = s1[r];
                lnp2[(quad * 4 + r) * 4 + w] = s2[r];
            }
        }
        __syncthreads();
        #pragma unroll
        for (int r = 0; r < 4; ++r) {
            floatx4 p1 = *(const floatx4*)&lnp1[(quad * 4 + r) * 4];  // broadcast
            floatx4 p2 = *(const floatx4*)&lnp2[(quad * 4 + r) * 4];
            float S1 = (p1[0] + p1[1]) + (p1[2] + p1[3]);
            float S2 = (p2[0] + p2[1]) + (p2[2] + p2[3]);
            float mu = S1 * (1.f / 64.f);
            float var = S2 * (1.f / 64.f) - mu * mu;
            xn[r] = (y[r] - mu) * rsqrtf(var + 1e-5f) * g1v + b1v;
            xbf[(quad * 4 + r) * 72 + ecol] = (_Float16)xn[r];
        }
    }
    __syncthreads();   // xbf visible

    {   // stage 2: relu(x@W1.T + b1) -> hbf
        floatx4 acc = zf4;
        #pragma unroll
        for (int kt = 0; kt < 4; ++kt) {
            half4 a4 = *(const half4*)&xbf[l16 * 72 + kt * 16 + quad * 4];
            float4 wv = *(const float4*)(W1 + (size_t)ecol * 64 + kt * 16 + quad * 4);
            half4 b4;
            b4[0] = (_Float16)wv.x; b4[1] = (_Float16)wv.y;
            b4[2] = (_Float16)wv.z; b4[3] = (_Float16)wv.w;
            acc = __builtin_amdgcn_mfma_f32_16x16x16f16(a4, b4, acc, 0, 0, 0);
        }
        const float b1v = b1[ecol];
        #pragma unroll
        for (int r = 0; r < 4; ++r)
            hbf[(quad * 4 + r) * 72 + ecol] = (_Float16)fmaxf(acc[r] + b1v, 0.f);
    }
    __syncthreads();   // hbf visible

    {   // stage 3: h@W2.T + b2 + x -> LN2 -> out
        floatx4 acc = zf4;
        #pragma unroll
        for (int kt = 0; kt < 4; ++kt) {
            half4 a4 = *(const half4*)&hbf[l16 * 72 + kt * 16 + quad * 4];
            float4 wv = *(const float4*)(W2 + (size_t)ecol * 64 + kt * 16 + quad * 4);
            half4 b4;
            b4[0] = (_Float16)wv.x; b4[1] = (_Float16)wv.y;
            b4[2] = (_Float16)wv.z; b4[3] = (_Float16)wv.w;
            acc = __builtin_amdgcn_mfma_f32_16x16x16f16(a4, b4, acc, 0, 0, 0);
        }
        const float b2v = b2[ecol], g2v = ln2g[ecol], be2v = ln2b[ecol];
        float s1[4], s2[4];
        #pragma unroll
        for (int r = 0; r < 4; ++r) {
            y[r] = acc[r] + b2v + xn[r];
            s1[r] = y[r]; s2[r] = y[r] * y[r];
        }
        #pragma unroll
        for (int o = 1; o < 16; o <<= 1) {
            #pragma unroll
            for (int r = 0; r < 4; ++r) {
                s1[r] += __shfl_xor(s1[r], o);
                s2[r] += __shfl_xor(s2[r], o);
            }
        }
        if (l16 == 0) {
            #pragma unroll
            for (int r = 0; r < 4; ++r) {
                lnp1[(quad * 4 + r) * 4 + w] = s1[r];
                lnp2[(quad * 4 + r) * 4 + w] = s2[r];
            }
        }
        __syncthreads();
        #pragma unroll
        for (int r = 0; r < 4; ++r) {
            floatx4 p1 = *(const floatx4*)&lnp1[(quad * 4 + r) * 4];
            floatx4 p2 = *(const floatx4*)&lnp2[(quad * 4 + r) * 4];
            float S1 = (p1[0] + p1[1]) + (p1[2] + p1[3]);
            float S2 = (p2[0] + p2[1]) + (p2[2] + p2[3]);
            float mu = S1 * (1.f / 64.f);
            float var = S2 * (1.f / 64.f) - mu * mu;
            float o2 = (y[r] - mu) * rsqrtf(var + 1e-5f) * g2v + be2v;
            out[(orow + quad * 4 + r) * 64 + ecol] = o2;
        }
    }
}

extern "C" void kernel_launch(void* const* d_in, const int* in_sizes, int n_in,
                              void* d_out, int out_size, void* d_ws, size_t ws_size,
                              hipStream_t stream)
{
    (void)in_sizes; (void)n_in; (void)out_size; (void)ws_size;
    const float* q    = (const float*)d_in[0];
    const float* k    = (const float*)d_in[1];
    const float* prev = (const float*)d_in[2];
    const float* Wq   = (const float*)d_in[3];
    const float* bq   = (const float*)d_in[4];
    const float* Wk   = (const float*)d_in[5];
    const float* bk   = (const float*)d_in[6];
    const float* Wv   = (const float*)d_in[7];
    const float* bv   = (const float*)d_in[8];
    const float* Wo   = (const float*)d_in[9];
    const float* bo   = (const float*)d_in[10];
    const float* g1   = (const float*)d_in[11];
    const float* be1  = (const float*)d_in[12];
    const float* W1   = (const float*)d_in[13];
    const float* b1   = (const float*)d_in[14];
    const float* W2   = (const float*)d_in[15];
    const float* b2   = (const float*)d_in[16];
    const float* g2   = (const float*)d_in[17];
    const float* be2  = (const float*)d_in[18];

    float* out  = (float*)d_out;
    float* attn = out + (size_t)64 * 512 * 64;

    _Float16* qws   = (_Float16*)d_ws;                    // [B][L][E]
    _Float16* kfrag = qws   + (size_t)64 * 512 * 64;      // [B][H][C][16][8]
    _Float16* vfrag = kfrag + (size_t)64 * 512 * 64;      // [B][H][C][8][16]

    ga_proj<<<dim3(512, 3), 256, 0, stream>>>(q, k, Wq, bq, Wk, bk, Wv, bv,
                                              qws, kfrag, vfrag);
    ga_attn<<<dim3(2048), 256, 0, stream>>>(qws, kfrag, vfrag, prev, Wo, bo,
                                            g1, be1, W1, b1, W2, b2, g2, be2,
                                            out, attn);
}

// Round 9
// 212.883 us; speedup vs baseline: 1.3808x; 1.3808x over previous
//
#include <hip/hip_runtime.h>

// GuidedAttention: B=64, Lq=Lk=512, E=64, H=8, D=8
// out  = [B,512,64] fp32, attn_wts = [B,512,512] fp32 (concatenated in d_out)
//
// v10 = v9 with launch_bounds reverted to (256,4).
// R8 post-mortem: (256,6) capped VGPR at ~80 < live ~90-100 -> scratch spill
// (WRITE 74->262MB, FETCH 12->68MB, dur 109->181us). Third occurrence of the
// same failure mode (R2/R5/R8): a cap below the live set is always worse than
// the occupancy it buys. (256,4) = cap 128 is the R7-proven-safe config.
//
// Structure (v8+v9, unchanged):
//  - ga_proj: f16 MFMA projection; emits K/V in FRAGMENT-MAJOR layout
//    (kfrag[b][h][c][key16][8e], vfrag[b][h][c][d8][key16]) so one MFMA
//    A-frag = one coalesced 256B wave load, L2-hot (XCD swizzle b=bx&63).
//  - ga_attn: two-pass softmax. Pass A: head-per-wave denominators (shfl
//    only, nothing persisted). Pass B: key-split with inv pre-known, QK
//    recomputed (bitwise-identical), attn_wts in 8 reg floatx4 (wave-
//    exclusive cols, direct store), PV online, ctx via LDS atomics.
//    3 barriers in attention, 0 bank conflicts, no parks.
//  - MFMA epilogue: Wo/W1/W2 matmuls as 4 mfma/wave each; A-frags from LDS,
//    B-frags = W direct from global (12 gather loads/wave, L1-hot); LN row
//    stats via 16-wide shfl + 512B cross-wave partials. LDS total 12.3KB.

using half4   = __attribute__((ext_vector_type(4))) _Float16;
using floatx4 = __attribute__((ext_vector_type(4))) float;

// ---------------------------------------------------------------- projection
// out[row][e] = sum_k x[row][k] * W[e][k]  (+bias; type0 also *scale*log2e)
// MFMA 16x16x16: A[m=row][k] from x, B[k][n=e] from W (B-frag lane reads
// W[n0+l16][kt*16+quad*4..]), C[m=quad*4+r][n=l16].
__global__ __launch_bounds__(256) void ga_proj(
    const float* __restrict__ q, const float* __restrict__ k,
    const float* __restrict__ Wq, const float* __restrict__ bq,
    const float* __restrict__ Wk, const float* __restrict__ bk,
    const float* __restrict__ Wv, const float* __restrict__ bv,
    _Float16* __restrict__ qws, _Float16* __restrict__ kfrag,
    _Float16* __restrict__ vfrag)
{
    const int type = blockIdx.y;                 // 0=q, 1=k, 2=v
    const int row0 = blockIdx.x * 64;            // 64 token-rows per block
    const float* __restrict__ src  = (type == 0) ? q : k;
    const float* __restrict__ W    = (type == 0) ? Wq : (type == 1) ? Wk : Wv;
    const float* __restrict__ bias = (type == 0) ? bq : (type == 1) ? bk : bv;

    __shared__ _Float16 xb16[64 * 72];   // x rows f16, stride 72
    __shared__ _Float16 wb16[64 * 72];   // W [e][k] f16

    const int t = threadIdx.x;
    #pragma unroll
    for (int j = 0; j < 4; ++j) {                // stage x and W, f32 -> f16
        int f = t + 256 * j;                     // 1024 float4 = 64x64
        int row = f >> 4, k0 = (f & 15) << 2;
        float4 v4 = *(const float4*)(src + (size_t)(row0 + row) * 64 + k0);
        half4 h4;
        h4[0] = (_Float16)v4.x; h4[1] = (_Float16)v4.y;
        h4[2] = (_Float16)v4.z; h4[3] = (_Float16)v4.w;
        *(half4*)&xb16[row * 72 + k0] = h4;
        float4 w4 = *(const float4*)(W + row * 64 + k0);
        half4 g4;
        g4[0] = (_Float16)w4.x; g4[1] = (_Float16)w4.y;
        g4[2] = (_Float16)w4.z; g4[3] = (_Float16)w4.w;
        *(half4*)&wb16[row * 72 + k0] = g4;
    }
    __syncthreads();

    const int lane = t & 63;
    const int w = t >> 6;            // wave owns 16 rows
    const int quad = lane >> 4;
    const int l16 = lane & 15;
    const int m0 = w * 16;
    const int grow = row0 + m0;      // global row base (multiple of 16)
    const int bb = grow >> 9;        // batch
    const int cc = (grow & 511) >> 4;// key-chunk (constant per wave)
    const floatx4 zf4 = {0.f, 0.f, 0.f, 0.f};

    #pragma unroll
    for (int n = 0; n < 4; ++n) {    // output-col tiles of 16
        floatx4 acc = zf4;
        #pragma unroll
        for (int kt = 0; kt < 4; ++kt) {
            half4 a4 = *(const half4*)&xb16[(m0 + l16) * 72 + kt * 16 + quad * 4];
            half4 b4 = *(const half4*)&wb16[(n * 16 + l16) * 72 + kt * 16 + quad * 4];
            acc = __builtin_amdgcn_mfma_f32_16x16x16f16(a4, b4, acc, 0, 0, 0);
        }
        const int e = n * 16 + l16;
        const float bv = bias[e];
        #pragma unroll
        for (int r = 0; r < 4; ++r) {
            float a = acc[r] + bv;
            if (type == 0) a *= 0.51012811866f;  // 1/sqrt(8) * log2(e)
            _Float16 hv = (_Float16)a;
            const int kk = quad * 4 + r;         // row-in-chunk / key16
            if (type == 0)
                qws[(size_t)(grow + kk) * 64 + e] = hv;
            else if (type == 1)   // kfrag[b][h][c][key16][8e]
                kfrag[((size_t)(bb * 8 + (e >> 3)) * 32 + cc) * 128
                      + kk * 8 + (e & 7)] = hv;
            else                  // vfrag[b][h][c][d8][key16]
                vfrag[((size_t)(bb * 8 + (e >> 3)) * 32 + cc) * 128
                      + (e & 7) * 16 + kk] = hv;
        }
    }
}

// ---------------------------------------------------------------- attention + epilogue
__global__ __launch_bounds__(256, 4) void ga_attn(
    const _Float16* __restrict__ qws, const _Float16* __restrict__ kfrag,
    const _Float16* __restrict__ vfrag,
    const float* __restrict__ prev,
    const float* __restrict__ Wo, const float* __restrict__ bo,
    const float* __restrict__ ln1g, const float* __restrict__ ln1b,
    const float* __restrict__ W1, const float* __restrict__ b1,
    const float* __restrict__ W2, const float* __restrict__ b2,
    const float* __restrict__ ln2g, const float* __restrict__ ln2b,
    float* __restrict__ out, float* __restrict__ attn)
{
    // 12,288 B LDS; VGPR cap 128 (R7-proven: live ~56-96, no spill)
    __shared__ __align__(16) unsigned char smem[12288];
    _Float16* qb   = (_Float16*)smem;              // [16][72] f16     2304 B
    float*    inv8 = (float*)(smem + 2304);        // [8][16]  f32      512 B
    float*    ctxb = (float*)(smem + 2816);        // [16][68] f32     4352 B
    _Float16* xbf  = (_Float16*)(smem + 7168);     // [16][72] f16     2304 B
    _Float16* hbf  = (_Float16*)(smem + 9472);     // [16][72] f16     2304 B
    float*    lnp1 = (float*)(smem + 11776);       // [16][4]  f32      256 B
    float*    lnp2 = (float*)(smem + 12032);       // [16][4]  f32      256 B

    const int t = threadIdx.x;
    const int lane = t & 63;
    const int w = t >> 6;            // wave 0..3
    const int quad = lane >> 4;
    const int l16 = lane & 15;
    // XCD swizzle: b = bx&63 -> all 32 tiles of batch b on XCD b%8 (L2 locality)
    const int b  = blockIdx.x & 63;
    const int l0 = (blockIdx.x >> 6) << 4;

    const _Float16* kfb = kfrag + (size_t)b * 32768;   // 8h x 32c x 128
    const _Float16* vfb = vfrag + (size_t)b * 32768;

    // ---- stage Q tile (16 rows), zero ctx
    if (t < 128) {
        int row = t >> 3, off = (t & 7) << 3;
        *(float4*)&qb[row * 72 + off] =
            *(const float4*)(qws + ((size_t)b * 512 + l0 + row) * 64 + off);
    }
    for (int i = t; i < 16 * 68; i += 256) ctxb[i] = 0.f;
    __syncthreads();

    const floatx4 zf4 = {0.f, 0.f, 0.f, 0.f};
    const _Float16 hz = (_Float16)0.f;

    // ---- pass A: denominators. wave w owns heads {w, w+4}, all 512 keys.
    #pragma unroll 1
    for (int hi = 0; hi < 2; ++hi) {
        const int h = hi * 4 + w;
        half4 bfrag = {hz, hz, hz, hz};
        if (quad < 2) bfrag = *(const half4*)&qb[l16 * 72 + h * 8 + quad * 4];
        const _Float16* kb = kfb + (size_t)h * 4096 + l16 * 8 + (quad & 1) * 4;
        float psum = 0.f;
        #pragma unroll 8
        for (int c = 0; c < 32; ++c) {
            // A[m=key16=l16][k]: k>=8 duplicates k<8 (finite; bfrag=0 there)
            half4 af = *(const half4*)(kb + c * 128);
            floatx4 sv = __builtin_amdgcn_mfma_f32_16x16x16f16(af, bfrag, zf4, 0, 0, 0);
            psum += (exp2f(sv[0]) + exp2f(sv[1])) + (exp2f(sv[2]) + exp2f(sv[3]));
        }
        psum += __shfl_xor(psum, 16);   // quads hold disjoint key subsets
        psum += __shfl_xor(psum, 32);
        if (lane < 16) inv8[h * 16 + l16] = 1.0f / psum;
    }
    __syncthreads();

    // ---- pass B: key-split (wave w owns keys [w*128,+128)), inv pre-known.
    // No per-head barrier. attn accumulates in regs (wave-exclusive columns).
    floatx4 attn_acc[8];
    #pragma unroll
    for (int i = 0; i < 8; ++i) attn_acc[i] = zf4;

    #pragma unroll 1
    for (int h = 0; h < 8; ++h) {
        half4 bfrag = {hz, hz, hz, hz};
        if (quad < 2) bfrag = *(const half4*)&qb[l16 * 72 + h * 8 + quad * 4];
        const float inv = inv8[h * 16 + l16];
        const _Float16* kb = kfb + ((size_t)h * 32 + w * 8) * 128 + l16 * 8 + (quad & 1) * 4;
        const _Float16* vb = vfb + ((size_t)h * 32 + w * 8) * 128 + (l16 & 7) * 16 + quad * 4;
        floatx4 cacc0 = zf4, cacc1 = zf4;
        #pragma unroll
        for (int c = 0; c < 8; ++c) {
            half4 af = *(const half4*)(kb + c * 128);
            floatx4 sv = __builtin_amdgcn_mfma_f32_16x16x16f16(af, bfrag, zf4, 0, 0, 0);
            float e0 = exp2f(sv[0]), e1 = exp2f(sv[1]);
            float e2 = exp2f(sv[2]), e3 = exp2f(sv[3]);
            floatx4 ev; ev[0] = e0 * inv; ev[1] = e1 * inv;
            ev[2] = e2 * inv; ev[3] = e3 * inv;
            attn_acc[c] += ev;
            half4 ph;
            ph[0] = (_Float16)e0; ph[1] = (_Float16)e1;
            ph[2] = (_Float16)e2; ph[3] = (_Float16)e3;
            // A-frag = V^T: A[d=l16&7][k=key=quad*4+j]; P^T C-layout == B-layout
            half4 vf = *(const half4*)(vb + c * 128);
            if (c & 1) cacc1 = __builtin_amdgcn_mfma_f32_16x16x16f16(vf, ph, cacc1, 0, 0, 0);
            else       cacc0 = __builtin_amdgcn_mfma_f32_16x16x16f16(vf, ph, cacc0, 0, 0, 0);
        }
        floatx4 cs = (cacc0 + cacc1) * inv;
        if (quad < 2) {                  // ctx^T[d=quad*4+r][q=l16], d<8 real
            #pragma unroll
            for (int r = 0; r < 4; ++r)
                atomicAdd(&ctxb[l16 * 68 + h * 8 + quad * 4 + r], cs[r]);
        }
    }
    // attn_wts store: rows=l16, this wave's 128 key-cols (mean over heads)
    {
        float* ap = attn + ((size_t)b * 512 + l0 + l16) * 512 + w * 128 + quad * 4;
        #pragma unroll
        for (int c = 0; c < 8; ++c)
            *(floatx4*)(ap + c * 16) = attn_acc[c] * 0.125f;
    }
    __syncthreads();   // ctx atomics complete

    // ---- MFMA epilogue. out[l][e] = ...: A[m=l][k], B[k][n=e]=W[e][k];
    // lane's C covers rows l=quad*4+r, col e=w*16+l16 (same mapping as proj).
    const int ecol = w * 16 + l16;
    const size_t orow = (size_t)b * 512 + l0;
    float y[4], xn[4];

    {   // stage 1: ctx@Wo.T + bo + prev -> LN1 -> xbf (+xn regs for residual)
        floatx4 acc = zf4;
        #pragma unroll
        for (int kt = 0; kt < 4; ++kt) {
            floatx4 cx = *(const floatx4*)&ctxb[l16 * 68 + kt * 16 + quad * 4];
            half4 a4;
            a4[0] = (_Float16)cx[0]; a4[1] = (_Float16)cx[1];
            a4[2] = (_Float16)cx[2]; a4[3] = (_Float16)cx[3];
            float4 wv = *(const float4*)(Wo + (size_t)ecol * 64 + kt * 16 + quad * 4);
            half4 b4;
            b4[0] = (_Float16)wv.x; b4[1] = (_Float16)wv.y;
            b4[2] = (_Float16)wv.z; b4[3] = (_Float16)wv.w;
            acc = __builtin_amdgcn_mfma_f32_16x16x16f16(a4, b4, acc, 0, 0, 0);
        }
        const float bov = bo[ecol], g1v = ln1g[ecol], b1v = ln1b[ecol];
        float s1[4], s2[4];
        #pragma unroll
        for (int r = 0; r < 4; ++r) {
            y[r] = acc[r] + bov + prev[(orow + quad * 4 + r) * 64 + ecol];
            s1[r] = y[r]; s2[r] = y[r] * y[r];
        }
        #pragma unroll
        for (int o = 1; o < 16; o <<= 1) {
            #pragma unroll
            for (int r = 0; r < 4; ++r) {
                s1[r] += __shfl_xor(s1[r], o);
                s2[r] += __shfl_xor(s2[r], o);
            }
        }
        if (l16 == 0) {
            #pragma unroll
            for (int r = 0; r < 4; ++r) {
                lnp1[(quad * 4 + r) * 4 + w] = s1[r];
                lnp2[(quad * 4 + r) * 4 + w] = s2[r];
            }
        }
        __syncthreads();
        #pragma unroll
        for (int r = 0; r < 4; ++r) {
            floatx4 p1 = *(const floatx4*)&lnp1[(quad * 4 + r) * 4];  // broadcast
            floatx4 p2 = *(const floatx4*)&lnp2[(quad * 4 + r) * 4];
            float S1 = (p1[0] + p1[1]) + (p1[2] + p1[3]);
            float S2 = (p2[0] + p2[1]) + (p2[2] + p2[3]);
            float mu = S1 * (1.f / 64.f);
            float var = S2 * (1.f / 64.f) - mu * mu;
            xn[r] = (y[r] - mu) * rsqrtf(var + 1e-5f) * g1v + b1v;
            xbf[(quad * 4 + r) * 72 + ecol] = (_Float16)xn[r];
        }
    }
    __syncthreads();   // xbf visible

    {   // stage 2: relu(x@W1.T + b1) -> hbf
        floatx4 acc = zf4;
        #pragma unroll
        for (int kt = 0; kt < 4; ++kt) {
            half4 a4 = *(const half4*)&xbf[l16 * 72 + kt * 16 + quad * 4];
            float4 wv = *(const float4*)(W1 + (size_t)ecol * 64 + kt * 16 + quad * 4);
            half4 b4;
            b4[0] = (_Float16)wv.x; b4[1] = (_Float16)wv.y;
            b4[2] = (_Float16)wv.z; b4[3] = (_Float16)wv.w;
            acc = __builtin_amdgcn_mfma_f32_16x16x16f16(a4, b4, acc, 0, 0, 0);
        }
        const float b1v = b1[ecol];
        #pragma unroll
        for (int r = 0; r < 4; ++r)
            hbf[(quad * 4 + r) * 72 + ecol] = (_Float16)fmaxf(acc[r] + b1v, 0.f);
    }
    __syncthreads();   // hbf visible

    {   // stage 3: h@W2.T + b2 + x -> LN2 -> out
        floatx4 acc = zf4;
        #pragma unroll
        for (int kt = 0; kt < 4; ++kt) {
            half4 a4 = *(const half4*)&hbf[l16 * 72 + kt * 16 + quad * 4];
            float4 wv = *(const float4*)(W2 + (size_t)ecol * 64 + kt * 16 + quad * 4);
            half4 b4;
            b4[0] = (_Float16)wv.x; b4[1] = (_Float16)wv.y;
            b4[2] = (_Float16)wv.z; b4[3] = (_Float16)wv.w;
            acc = __builtin_amdgcn_mfma_f32_16x16x16f16(a4, b4, acc, 0, 0, 0);
        }
        const float b2v = b2[ecol], g2v = ln2g[ecol], be2v = ln2b[ecol];
        float s1[4], s2[4];
        #pragma unroll
        for (int r = 0; r < 4; ++r) {
            y[r] = acc[r] + b2v + xn[r];
            s1[r] = y[r]; s2[r] = y[r] * y[r];
        }
        #pragma unroll
        for (int o = 1; o < 16; o <<= 1) {
            #pragma unroll
            for (int r = 0; r < 4; ++r) {
                s1[r] += __shfl_xor(s1[r], o);
                s2[r] += __shfl_xor(s2[r], o);
            }
        }
        if (l16 == 0) {
            #pragma unroll
            for (int r = 0; r < 4; ++r) {
                lnp1[(quad * 4 + r) * 4 + w] = s1[r];
                lnp2[(quad * 4 + r) * 4 + w] = s2[r];
            }
        }
        __syncthreads();
        #pragma unroll
        for (int r = 0; r < 4; ++r) {
            floatx4 p1 = *(const floatx4*)&lnp1[(quad * 4 + r) * 4];
            floatx4 p2 = *(const floatx4*)&lnp2[(quad * 4 + r) * 4];
            float S1 = (p1[0] + p1[1]) + (p1[2] + p1[3]);
            float S2 = (p2[0] + p2[1]) + (p2[2] + p2[3]);
            float mu = S1 * (1.f / 64.f);
            float var = S2 * (1.f / 64.f) - mu * mu;
            float o2 = (y[r] - mu) * rsqrtf(var + 1e-5f) * g2v + be2v;
            out[(orow + quad * 4 + r) * 64 + ecol] = o2;
        }
    }
}

extern "C" void kernel_launch(void* const* d_in, const int* in_sizes, int n_in,
                              void* d_out, int out_size, void* d_ws, size_t ws_size,
                              hipStream_t stream)
{
    (void)in_sizes; (void)n_in; (void)out_size; (void)ws_size;
    const float* q    = (const float*)d_in[0];
    const float* k    = (const float*)d_in[1];
    const float* prev = (const float*)d_in[2];
    const float* Wq   = (const float*)d_in[3];
    const float* bq   = (const float*)d_in[4];
    const float* Wk   = (const float*)d_in[5];
    const float* bk   = (const float*)d_in[6];
    const float* Wv   = (const float*)d_in[7];
    const float* bv   = (const float*)d_in[8];
    const float* Wo   = (const float*)d_in[9];
    const float* bo   = (const float*)d_in[10];
    const float* g1   = (const float*)d_in[11];
    const float* be1  = (const float*)d_in[12];
    const float* W1   = (const float*)d_in[13];
    const float* b1   = (const float*)d_in[14];
    const float* W2   = (const float*)d_in[15];
    const float* b2   = (const float*)d_in[16];
    const float* g2   = (const float*)d_in[17];
    const float* be2  = (const float*)d_in[18];

    float* out  = (float*)d_out;
    float* attn = out + (size_t)64 * 512 * 64;

    _Float16* qws   = (_Float16*)d_ws;                    // [B][L][E]
    _Float16* kfrag = qws   + (size_t)64 * 512 * 64;      // [B][H][C][16][8]
    _Float16* vfrag = kfrag + (size_t)64 * 512 * 64;      // [B][H][C][8][16]

    ga_proj<<<dim3(512, 3), 256, 0, stream>>>(q, k, Wq, bq, Wk, bk, Wv, bv,
                                              qws, kfrag, vfrag);
    ga_attn<<<dim3(2048), 256, 0, stream>>>(qws, kfrag, vfrag, prev, Wo, bo,
                                            g1, be1, W1, b1, W2, b2, g2, be2,
                                            out, attn);
}

// Round 11
// 200.137 us; speedup vs baseline: 1.4687x; 1.0637x over previous
//
#include <hip/hip_runtime.h>

// GuidedAttention: B=64, Lq=Lk=512, E=64, H=8, D=8
// out  = [B,512,64] fp32, attn_wts = [B,512,512] fp32 (concatenated in d_out)
//
// v12 = v10 (R9, passed, 100.6us attn) + ONE change: exp2f -> raw v_exp_f32
// via __builtin_amdgcn_exp2f. R9 accounting: VALUBusy 67% <=> ~5K VALU
// instr/thread but source count is ~2.5K if exp2 were 1 instr -> libm
// __ocml_exp2_f32's range-fixup (~6 instr x 512 exps/thread) is ~60% of all
// VALU work. Args are bounded (|s| < 16) so the fixup path is dead.
// R10's inline-asm version produced NaN (asm is opaque to the CDNA hazard
// recognizer -> garbage register); the BUILTIN emits the same v_exp_f32 with
// full compiler hazard handling. __has_builtin guard -> cannot fail compile.
//
// Structure (v8-v10, proven):
//  - ga_proj: f16 MFMA projection; K/V emitted in FRAGMENT-MAJOR layout
//    (kfrag[b][h][c][key16][8e], vfrag[b][h][c][d8][key16]): one MFMA A-frag
//    = one coalesced 256B wave load, L2-hot (XCD swizzle b=bx&63).
//  - ga_attn: two-pass softmax. Pass A: head-per-wave denominators (shfl
//    only). Pass B: key-split, inv pre-known, QK recomputed (bitwise-same),
//    attn_wts in 8 reg floatx4 (wave-exclusive cols), PV online, ctx via
//    LDS atomics. 3 barriers, 0 bank conflicts, no parks.
//  - MFMA epilogue: Wo/W1/W2 as 4 mfma/wave; W direct from global (L1-hot);
//    LN stats via 16-wide shfl + 512B cross-wave partials. LDS 12.3KB.
//  - launch_bounds(256,4): cap 128 >> live ~52 (R2/R5/R8 spill mode excluded).

using half4   = __attribute__((ext_vector_type(4))) _Float16;
using floatx4 = __attribute__((ext_vector_type(4))) float;

#if defined(__has_builtin)
#  if __has_builtin(__builtin_amdgcn_exp2f)
#    define EXP2(x) __builtin_amdgcn_exp2f(x)
#  else
#    define EXP2(x) exp2f(x)
#  endif
#else
#  define EXP2(x) exp2f(x)
#endif

// ---------------------------------------------------------------- projection
// out[row][e] = sum_k x[row][k] * W[e][k]  (+bias; type0 also *scale*log2e)
// MFMA 16x16x16: A[m=row][k] from x, B[k][n=e] from W (B-frag lane reads
// W[n0+l16][kt*16+quad*4..]), C[m=quad*4+r][n=l16].
__global__ __launch_bounds__(256) void ga_proj(
    const float* __restrict__ q, const float* __restrict__ k,
    const float* __restrict__ Wq, const float* __restrict__ bq,
    const float* __restrict__ Wk, const float* __restrict__ bk,
    const float* __restrict__ Wv, const float* __restrict__ bv,
    _Float16* __restrict__ qws, _Float16* __restrict__ kfrag,
    _Float16* __restrict__ vfrag)
{
    const int type = blockIdx.y;                 // 0=q, 1=k, 2=v
    const int row0 = blockIdx.x * 64;            // 64 token-rows per block
    const float* __restrict__ src  = (type == 0) ? q : k;
    const float* __restrict__ W    = (type == 0) ? Wq : (type == 1) ? Wk : Wv;
    const float* __restrict__ bias = (type == 0) ? bq : (type == 1) ? bk : bv;

    __shared__ _Float16 xb16[64 * 72];   // x rows f16, stride 72
    __shared__ _Float16 wb16[64 * 72];   // W [e][k] f16

    const int t = threadIdx.x;
    #pragma unroll
    for (int j = 0; j < 4; ++j) {                // stage x and W, f32 -> f16
        int f = t + 256 * j;                     // 1024 float4 = 64x64
        int row = f >> 4, k0 = (f & 15) << 2;
        float4 v4 = *(const float4*)(src + (size_t)(row0 + row) * 64 + k0);
        half4 h4;
        h4[0] = (_Float16)v4.x; h4[1] = (_Float16)v4.y;
        h4[2] = (_Float16)v4.z; h4[3] = (_Float16)v4.w;
        *(half4*)&xb16[row * 72 + k0] = h4;
        float4 w4 = *(const float4*)(W + row * 64 + k0);
        half4 g4;
        g4[0] = (_Float16)w4.x; g4[1] = (_Float16)w4.y;
        g4[2] = (_Float16)w4.z; g4[3] = (_Float16)w4.w;
        *(half4*)&wb16[row * 72 + k0] = g4;
    }
    __syncthreads();

    const int lane = t & 63;
    const int w = t >> 6;            // wave owns 16 rows
    const int quad = lane >> 4;
    const int l16 = lane & 15;
    const int m0 = w * 16;
    const int grow = row0 + m0;      // global row base (multiple of 16)
    const int bb = grow >> 9;        // batch
    const int cc = (grow & 511) >> 4;// key-chunk (constant per wave)
    const floatx4 zf4 = {0.f, 0.f, 0.f, 0.f};

    #pragma unroll
    for (int n = 0; n < 4; ++n) {    // output-col tiles of 16
        floatx4 acc = zf4;
        #pragma unroll
        for (int kt = 0; kt < 4; ++kt) {
            half4 a4 = *(const half4*)&xb16[(m0 + l16) * 72 + kt * 16 + quad * 4];
            half4 b4 = *(const half4*)&wb16[(n * 16 + l16) * 72 + kt * 16 + quad * 4];
            acc = __builtin_amdgcn_mfma_f32_16x16x16f16(a4, b4, acc, 0, 0, 0);
        }
        const int e = n * 16 + l16;
        const float bv = bias[e];
        #pragma unroll
        for (int r = 0; r < 4; ++r) {
            float a = acc[r] + bv;
            if (type == 0) a *= 0.51012811866f;  // 1/sqrt(8) * log2(e)
            _Float16 hv = (_Float16)a;
            const int kk = quad * 4 + r;         // row-in-chunk / key16
            if (type == 0)
                qws[(size_t)(grow + kk) * 64 + e] = hv;
            else if (type == 1)   // kfrag[b][h][c][key16][8e]
                kfrag[((size_t)(bb * 8 + (e >> 3)) * 32 + cc) * 128
                      + kk * 8 + (e & 7)] = hv;
            else                  // vfrag[b][h][c][d8][key16]
                vfrag[((size_t)(bb * 8 + (e >> 3)) * 32 + cc) * 128
                      + (e & 7) * 16 + kk] = hv;
        }
    }
}

// ---------------------------------------------------------------- attention + epilogue
__global__ __launch_bounds__(256, 4) void ga_attn(
    const _Float16* __restrict__ qws, const _Float16* __restrict__ kfrag,
    const _Float16* __restrict__ vfrag,
    const float* __restrict__ prev,
    const float* __restrict__ Wo, const float* __restrict__ bo,
    const float* __restrict__ ln1g, const float* __restrict__ ln1b,
    const float* __restrict__ W1, const float* __restrict__ b1,
    const float* __restrict__ W2, const float* __restrict__ b2,
    const float* __restrict__ ln2g, const float* __restrict__ ln2b,
    float* __restrict__ out, float* __restrict__ attn)
{
    // 12,288 B LDS; VGPR cap 128 (R9-proven: live ~52, no spill)
    __shared__ __align__(16) unsigned char smem[12288];
    _Float16* qb   = (_Float16*)smem;              // [16][72] f16     2304 B
    float*    inv8 = (float*)(smem + 2304);        // [8][16]  f32      512 B
    float*    ctxb = (float*)(smem + 2816);        // [16][68] f32     4352 B
    _Float16* xbf  = (_Float16*)(smem + 7168);     // [16][72] f16     2304 B
    _Float16* hbf  = (_Float16*)(smem + 9472);     // [16][72] f16     2304 B
    float*    lnp1 = (float*)(smem + 11776);       // [16][4]  f32      256 B
    float*    lnp2 = (float*)(smem + 12032);       // [16][4]  f32      256 B

    const int t = threadIdx.x;
    const int lane = t & 63;
    const int w = t >> 6;            // wave 0..3
    const int quad = lane >> 4;
    const int l16 = lane & 15;
    // XCD swizzle: b = bx&63 -> all 32 tiles of batch b on XCD b%8 (L2 locality)
    const int b  = blockIdx.x & 63;
    const int l0 = (blockIdx.x >> 6) << 4;

    const _Float16* kfb = kfrag + (size_t)b * 32768;   // 8h x 32c x 128
    const _Float16* vfb = vfrag + (size_t)b * 32768;

    // ---- stage Q tile (16 rows), zero ctx
    if (t < 128) {
        int row = t >> 3, off = (t & 7) << 3;
        *(float4*)&qb[row * 72 + off] =
            *(const float4*)(qws + ((size_t)b * 512 + l0 + row) * 64 + off);
    }
    for (int i = t; i < 16 * 68; i += 256) ctxb[i] = 0.f;
    __syncthreads();

    const floatx4 zf4 = {0.f, 0.f, 0.f, 0.f};
    const _Float16 hz = (_Float16)0.f;

    // ---- pass A: denominators. wave w owns heads {w, w+4}, all 512 keys.
    #pragma unroll 1
    for (int hi = 0; hi < 2; ++hi) {
        const int h = hi * 4 + w;
        half4 bfrag = {hz, hz, hz, hz};
        if (quad < 2) bfrag = *(const half4*)&qb[l16 * 72 + h * 8 + quad * 4];
        const _Float16* kb = kfb + (size_t)h * 4096 + l16 * 8 + (quad & 1) * 4;
        float psum = 0.f;
        #pragma unroll 8
        for (int c = 0; c < 32; ++c) {
            // A[m=key16=l16][k]: k>=8 duplicates k<8 (finite; bfrag=0 there)
            half4 af = *(const half4*)(kb + c * 128);
            floatx4 sv = __builtin_amdgcn_mfma_f32_16x16x16f16(af, bfrag, zf4, 0, 0, 0);
            psum += (EXP2(sv[0]) + EXP2(sv[1])) + (EXP2(sv[2]) + EXP2(sv[3]));
        }
        psum += __shfl_xor(psum, 16);   // quads hold disjoint key subsets
        psum += __shfl_xor(psum, 32);
        if (lane < 16) inv8[h * 16 + l16] = 1.0f / psum;
    }
    __syncthreads();

    // ---- pass B: key-split (wave w owns keys [w*128,+128)), inv pre-known.
    // No per-head barrier. attn accumulates in regs (wave-exclusive columns).
    floatx4 attn_acc[8];
    #pragma unroll
    for (int i = 0; i < 8; ++i) attn_acc[i] = zf4;

    #pragma unroll 1
    for (int h = 0; h < 8; ++h) {
        half4 bfrag = {hz, hz, hz, hz};
        if (quad < 2) bfrag = *(const half4*)&qb[l16 * 72 + h * 8 + quad * 4];
        const float inv = inv8[h * 16 + l16];
        const _Float16* kb = kfb + ((size_t)h * 32 + w * 8) * 128 + l16 * 8 + (quad & 1) * 4;
        const _Float16* vb = vfb + ((size_t)h * 32 + w * 8) * 128 + (l16 & 7) * 16 + quad * 4;
        floatx4 cacc0 = zf4, cacc1 = zf4;
        #pragma unroll
        for (int c = 0; c < 8; ++c) {
            half4 af = *(const half4*)(kb + c * 128);
            floatx4 sv = __builtin_amdgcn_mfma_f32_16x16x16f16(af, bfrag, zf4, 0, 0, 0);
            float e0 = EXP2(sv[0]), e1 = EXP2(sv[1]);
            float e2 = EXP2(sv[2]), e3 = EXP2(sv[3]);
            floatx4 ev; ev[0] = e0 * inv; ev[1] = e1 * inv;
            ev[2] = e2 * inv; ev[3] = e3 * inv;
            attn_acc[c] += ev;
            half4 ph;
            ph[0] = (_Float16)e0; ph[1] = (_Float16)e1;
            ph[2] = (_Float16)e2; ph[3] = (_Float16)e3;
            // A-frag = V^T: A[d=l16&7][k=key=quad*4+j]; P^T C-layout == B-layout
            half4 vf = *(const half4*)(vb + c * 128);
            if (c & 1) cacc1 = __builtin_amdgcn_mfma_f32_16x16x16f16(vf, ph, cacc1, 0, 0, 0);
            else       cacc0 = __builtin_amdgcn_mfma_f32_16x16x16f16(vf, ph, cacc0, 0, 0, 0);
        }
        floatx4 cs = (cacc0 + cacc1) * inv;
        if (quad < 2) {                  // ctx^T[d=quad*4+r][q=l16], d<8 real
            #pragma unroll
            for (int r = 0; r < 4; ++r)
                atomicAdd(&ctxb[l16 * 68 + h * 8 + quad * 4 + r], cs[r]);
        }
    }
    // attn_wts store: rows=l16, this wave's 128 key-cols (mean over heads)
    {
        float* ap = attn + ((size_t)b * 512 + l0 + l16) * 512 + w * 128 + quad * 4;
        #pragma unroll
        for (int c = 0; c < 8; ++c)
            *(floatx4*)(ap + c * 16) = attn_acc[c] * 0.125f;
    }
    __syncthreads();   // ctx atomics complete

    // ---- MFMA epilogue. out[l][e] = ...: A[m=l][k], B[k][n=e]=W[e][k];
    // lane's C covers rows l=quad*4+r, col e=w*16+l16 (same mapping as proj).
    const int ecol = w * 16 + l16;
    const size_t orow = (size_t)b * 512 + l0;
    float y[4], xn[4];

    {   // stage 1: ctx@Wo.T + bo + prev -> LN1 -> xbf (+xn regs for residual)
        floatx4 acc = zf4;
        #pragma unroll
        for (int kt = 0; kt < 4; ++kt) {
            floatx4 cx = *(const floatx4*)&ctxb[l16 * 68 + kt * 16 + quad * 4];
            half4 a4;
            a4[0] = (_Float16)cx[0]; a4[1] = (_Float16)cx[1];
            a4[2] = (_Float16)cx[2]; a4[3] = (_Float16)cx[3];
            float4 wv = *(const float4*)(Wo + (size_t)ecol * 64 + kt * 16 + quad * 4);
            half4 b4;
            b4[0] = (_Float16)wv.x; b4[1] = (_Float16)wv.y;
            b4[2] = (_Float16)wv.z; b4[3] = (_Float16)wv.w;
            acc = __builtin_amdgcn_mfma_f32_16x16x16f16(a4, b4, acc, 0, 0, 0);
        }
        const float bov = bo[ecol], g1v = ln1g[ecol], b1v = ln1b[ecol];
        float s1[4], s2[4];
        #pragma unroll
        for (int r = 0; r < 4; ++r) {
            y[r] = acc[r] + bov + prev[(orow + quad * 4 + r) * 64 + ecol];
            s1[r] = y[r]; s2[r] = y[r] * y[r];
        }
        #pragma unroll
        for (int o = 1; o < 16; o <<= 1) {
            #pragma unroll
            for (int r = 0; r < 4; ++r) {
                s1[r] += __shfl_xor(s1[r], o);
                s2[r] += __shfl_xor(s2[r], o);
            }
        }
        if (l16 == 0) {
            #pragma unroll
            for (int r = 0; r < 4; ++r) {
                lnp1[(quad * 4 + r) * 4 + w] = s1[r];
                lnp2[(quad * 4 + r) * 4 + w] = s2[r];
            }
        }
        __syncthreads();
        #pragma unroll
        for (int r = 0; r < 4; ++r) {
            floatx4 p1 = *(const floatx4*)&lnp1[(quad * 4 + r) * 4];  // broadcast
            floatx4 p2 = *(const floatx4*)&lnp2[(quad * 4 + r) * 4];
            float S1 = (p1[0] + p1[1]) + (p1[2] + p1[3]);
            float S2 = (p2[0] + p2[1]) + (p2[2] + p2[3]);
            float mu = S1 * (1.f / 64.f);
            float var = S2 * (1.f / 64.f) - mu * mu;
            xn[r] = (y[r] - mu) * rsqrtf(var + 1e-5f) * g1v + b1v;
            xbf[(quad * 4 + r) * 72 + ecol] = (_Float16)xn[r];
        }
    }
    __syncthreads();   // xbf visible

    {   // stage 2: relu(x@W1.T + b1) -> hbf
        floatx4 acc = zf4;
        #pragma unroll
        for (int kt = 0; kt < 4; ++kt) {
            half4 a4 = *(const half4*)&xbf[l16 * 72 + kt * 16 + quad * 4];
            float4 wv = *(const float4*)(W1 + (size_t)ecol * 64 + kt * 16 + quad * 4);
            half4 b4;
            b4[0] = (_Float16)wv.x; b4[1] = (_Float16)wv.y;
            b4[2] = (_Float16)wv.z; b4[3] = (_Float16)wv.w;
            acc = __builtin_amdgcn_mfma_f32_16x16x16f16(a4, b4, acc, 0, 0, 0);
        }
        const float b1v = b1[ecol];
        #pragma unroll
        for (int r = 0; r < 4; ++r)
            hbf[(quad * 4 + r) * 72 + ecol] = (_Float16)fmaxf(acc[r] + b1v, 0.f);
    }
    __syncthreads();   // hbf visible

    {   // stage 3: h@W2.T + b2 + x -> LN2 -> out
        floatx4 acc = zf4;
        #pragma unroll
        for (int kt = 0; kt < 4; ++kt) {
            half4 a4 = *(const half4*)&hbf[l16 * 72 + kt * 16 + quad * 4];
            float4 wv = *(const float4*)(W2 + (size_t)ecol * 64 + kt * 16 + quad * 4);
            half4 b4;
            b4[0] = (_Float16)wv.x; b4[1] = (_Float16)wv.y;
            b4[2] = (_Float16)wv.z; b4[3] = (_Float16)wv.w;
            acc = __builtin_amdgcn_mfma_f32_16x16x16f16(a4, b4, acc, 0, 0, 0);
        }
        const float b2v = b2[ecol], g2v = ln2g[ecol], be2v = ln2b[ecol];
        float s1[4], s2[4];
        #pragma unroll
        for (int r = 0; r < 4; ++r) {
            y[r] = acc[r] + b2v + xn[r];
            s1[r] = y[r]; s2[r] = y[r] * y[r];
        }
        #pragma unroll
        for (int o = 1; o < 16; o <<= 1) {
            #pragma unroll
            for (int r = 0; r < 4; ++r) {
                s1[r] += __shfl_xor(s1[r], o);
                s2[r] += __shfl_xor(s2[r], o);
            }
        }
        if (l16 == 0) {
            #pragma unroll
            for (int r = 0; r < 4; ++r) {
                lnp1[(quad * 4 + r) * 4 + w] = s1[r];
                lnp2[(quad * 4 + r) * 4 + w] = s2[r];
            }
        }
        __syncthreads();
        #pragma unroll
        for (int r = 0; r < 4; ++r) {
            floatx4 p1 = *(const floatx4*)&lnp1[(quad * 4 + r) * 4];
            floatx4 p2 = *(const floatx4*)&lnp2[(quad * 4 + r) * 4];
            float S1 = (p1[0] + p1[1]) + (p1[2] + p1[3]);
            float S2 = (p2[0] + p2[1]) + (p2[2] + p2[3]);
            float mu = S1 * (1.f / 64.f);
            float var = S2 * (1.f / 64.f) - mu * mu;
            float o2 = (y[r] - mu) * rsqrtf(var + 1e-5f) * g2v + be2v;
            out[(orow + quad * 4 + r) * 64 + ecol] = o2;
        }
    }
}

extern "C" void kernel_launch(void* const* d_in, const int* in_sizes, int n_in,
                              void* d_out, int out_size, void* d_ws, size_t ws_size,
                              hipStream_t stream)
{
    (void)in_sizes; (void)n_in; (void)out_size; (void)ws_size;
    const float* q    = (const float*)d_in[0];
    const float* k    = (const float*)d_in[1];
    const float* prev = (const float*)d_in[2];
    const float* Wq   = (const float*)d_in[3];
    const float* bq   = (const float*)d_in[4];
    const float* Wk   = (const float*)d_in[5];
    const float* bk   = (const float*)d_in[6];
    const float* Wv   = (const float*)d_in[7];
    const float* bv   = (const float*)d_in[8];
    const float* Wo   = (const float*)d_in[9];
    const float* bo   = (const float*)d_in[10];
    const float* g1   = (const float*)d_in[11];
    const float* be1  = (const float*)d_in[12];
    const float* W1   = (const float*)d_in[13];
    const float* b1   = (const float*)d_in[14];
    const float* W2   = (const float*)d_in[15];
    const float* b2   = (const float*)d_in[16];
    const float* g2   = (const float*)d_in[17];
    const float* be2  = (const float*)d_in[18];

    float* out  = (float*)d_out;
    float* attn = out + (size_t)64 * 512 * 64;

    _Float16* qws   = (_Float16*)d_ws;                    // [B][L][E]
    _Float16* kfrag = qws   + (size_t)64 * 512 * 64;      // [B][H][C][16][8]
    _Float16* vfrag = kfrag + (size_t)64 * 512 * 64;      // [B][H][C][8][16]

    ga_proj<<<dim3(512, 3), 256, 0, stream>>>(q, k, Wq, bq, Wk, bk, Wv, bv,
                                              qws, kfrag, vfrag);
    ga_attn<<<dim3(2048), 256, 0, stream>>>(qws, kfrag, vfrag, prev, Wo, bo,
                                            g1, be1, W1, b1, W2, b2, g2, be2,
                                            out, attn);
}